// Round 3
// baseline (535.203 us; speedup 1.0000x reference)
//
#include <hip/hip_runtime.h>
#include <hip/hip_bf16.h>

#define PAD_VALUE -1000.0f

// Problem constants (from reference setup_inputs)
constexpr int B   = 4;
constexpr int T   = 24;
constexpr int C   = 10;
constexpr int H   = 128;
constexpr int W   = 128;
constexpr int Tc  = 365;
constexpr int Dc  = 11;
constexpr int HID = 64;
constexpr int Dm  = 64;
constexpr int HW  = H * W;     // 16384
constexpr int CO  = C + Dm;    // 74 output channels

// ---------------------------------------------------------------------------
// Kernel 1: per (b,t) date match + tiny MLP -> clim_feat[B*T][64] fp32.
// One block per (b,t), 64 threads. All float tensors are FP32 (reference
// dtype; confirmed: bf16 reinterpretation of inputs produced NaN in R1).
// Dates may arrive as int32 or int64; autodetect (int64 => all odd 32-bit
// words of dates_sat are 0, since values < 365 and nonnegative).
// ---------------------------------------------------------------------------
__global__ void clim_mlp_kernel(const int* __restrict__ dates_sat_raw,   // [B*T] (i32 or i64)
                                const float* __restrict__ input_clim,    // [B*Tc*Dc]
                                const int* __restrict__ dates_clim_raw,  // [B*Tc] (i32 or i64)
                                const float* __restrict__ W1,            // [Dc*HID]
                                const float* __restrict__ b1,            // [HID]
                                const float* __restrict__ W2,            // [HID*Dm]
                                const float* __restrict__ b2,            // [Dm]
                                float* __restrict__ feat_out) {          // [B*T*Dm] fp32
    const int bt  = blockIdx.x;         // 0..B*T-1
    const int b   = bt / T;
    const int tid = threadIdx.x;        // 0..63

    __shared__ int   s_idx;
    __shared__ int   s_is64;
    __shared__ float s_clim[Dc];
    __shared__ float s_h[HID];

    if (tid == 0) {
        s_idx = 0x7fffffff;
        int is64 = 1;
        for (int i = 1; i < B * T; i += 2) {
            if (dates_sat_raw[i] != 0) { is64 = 0; break; }
        }
        s_is64 = is64;
    }
    __syncthreads();
    const int is64 = s_is64;

    const int target = is64 ? dates_sat_raw[2 * bt] : dates_sat_raw[bt];

    // first climate index whose date equals the sat date
    int local = 0x7fffffff;
    for (int j = tid; j < Tc; j += 64) {
        const int e = b * Tc + j;
        const int dc = is64 ? dates_clim_raw[2 * e] : dates_clim_raw[e];
        if (dc == target) local = min(local, j);
    }
    if (local != 0x7fffffff) atomicMin(&s_idx, local);
    __syncthreads();

    const int  idx = s_idx;
    const bool has = idx < Tc;

    if (tid < Dc) {
        s_clim[tid] = has ? input_clim[(b * Tc + idx) * Dc + tid] : PAD_VALUE;
    }
    __syncthreads();

    // hidden layer: h[tid] = relu(sum_d clim[d]*W1[d][tid] + b1[tid])
    float acc = b1[tid];
#pragma unroll
    for (int d = 0; d < Dc; ++d)
        acc += s_clim[d] * W1[d * HID + tid];
    s_h[tid] = fmaxf(acc, 0.0f);
    __syncthreads();

    // output layer: feat[tid] = sum_j h[j]*W2[j][tid] + b2[tid]
    float acc2 = b2[tid];
#pragma unroll
    for (int j = 0; j < HID; ++j)
        acc2 += s_h[j] * W2[j * Dm + tid];

    feat_out[bt * Dm + tid] = acc2;
}

// ---------------------------------------------------------------------------
// Kernel 2: assemble output [B,T,74,H,W] fp32.
// One block per (b,t,c) plane of 16384 floats; 256 threads x 16 iters of
// float4 (16 B/lane) stores. Channels < C copy sat; channels >= C splat
// one fp32 clim_feat value.
// ---------------------------------------------------------------------------
__global__ __launch_bounds__(256)
void assemble_kernel(const float* __restrict__ input_sat,  // [B*T*C*HW] fp32
                     const float* __restrict__ feat,       // [B*T*Dm] fp32
                     float* __restrict__ out) {            // [B*T*CO*HW] fp32
    const int plane = blockIdx.x;       // 0 .. B*T*CO-1
    const int c  = plane % CO;
    const int bt = plane / CO;

    float4* __restrict__ dst4 = reinterpret_cast<float4*>(out + (size_t)plane * HW);
    constexpr int NVEC = HW / 4;        // 4096 float4 per plane

    if (c < C) {
        const float4* __restrict__ src4 = reinterpret_cast<const float4*>(
            input_sat + (size_t)(bt * C + c) * HW);
        for (int i = threadIdx.x; i < NVEC; i += 256)
            dst4[i] = src4[i];
    } else {
        const float v = feat[bt * Dm + (c - C)];
        const float4 splat = make_float4(v, v, v, v);
        for (int i = threadIdx.x; i < NVEC; i += 256)
            dst4[i] = splat;
    }
}

// ---------------------------------------------------------------------------
extern "C" void kernel_launch(void* const* d_in, const int* in_sizes, int n_in,
                              void* d_out, int out_size, void* d_ws, size_t ws_size,
                              hipStream_t stream) {
    const float* input_sat  = (const float*)d_in[0];
    const int*   dates_sat  = (const int*)d_in[1];
    const float* input_clim = (const float*)d_in[2];
    const int*   dates_clim = (const int*)d_in[3];
    const float* W1p        = (const float*)d_in[4];
    const float* b1p        = (const float*)d_in[5];
    const float* W2p        = (const float*)d_in[6];
    const float* b2p        = (const float*)d_in[7];

    float* feat = (float*)d_ws;    // B*T*Dm fp32 (24 KB scratch)
    float* out  = (float*)d_out;   // fp32 output (reference output dtype)

    clim_mlp_kernel<<<B * T, 64, 0, stream>>>(dates_sat, input_clim, dates_clim,
                                              W1p, b1p, W2p, b2p, feat);

    assemble_kernel<<<B * T * CO, 256, 0, stream>>>(input_sat, feat, out);
}

// Round 5
// 520.980 us; speedup vs baseline: 1.0273x; 1.0273x over previous
//
#include <hip/hip_runtime.h>
#include <hip/hip_bf16.h>

#define PAD_VALUE -1000.0f

// Problem constants (from reference setup_inputs)
constexpr int B   = 4;
constexpr int T   = 24;
constexpr int C   = 10;
constexpr int H   = 128;
constexpr int W   = 128;
constexpr int Tc  = 365;
constexpr int Dc  = 11;
constexpr int HID = 64;
constexpr int Dm  = 64;
constexpr int HW  = H * W;     // 16384
constexpr int CO  = C + Dm;    // 74 output channels

// Native clang vector type — __builtin_nontemporal_* requires a real vector,
// not HIP's struct-wrapped float4.
typedef float vfloat4 __attribute__((ext_vector_type(4)));

// ---------------------------------------------------------------------------
// Kernel 1: per (b,t) date match + tiny MLP -> clim_feat[B*T][64] fp32.
// One block per (b,t), 64 threads. All float tensors are FP32.
// Dates may arrive as int32 or int64; autodetect (int64 => all odd 32-bit
// words of dates_sat are 0, since values < 365 and nonnegative).
// ---------------------------------------------------------------------------
__global__ void clim_mlp_kernel(const int* __restrict__ dates_sat_raw,   // [B*T] (i32 or i64)
                                const float* __restrict__ input_clim,    // [B*Tc*Dc]
                                const int* __restrict__ dates_clim_raw,  // [B*Tc] (i32 or i64)
                                const float* __restrict__ W1,            // [Dc*HID]
                                const float* __restrict__ b1,            // [HID]
                                const float* __restrict__ W2,            // [HID*Dm]
                                const float* __restrict__ b2,            // [Dm]
                                float* __restrict__ feat_out) {          // [B*T*Dm] fp32
    const int bt  = blockIdx.x;         // 0..B*T-1
    const int b   = bt / T;
    const int tid = threadIdx.x;        // 0..63

    __shared__ int   s_idx;
    __shared__ int   s_is64;
    __shared__ float s_clim[Dc];
    __shared__ float s_h[HID];

    if (tid == 0) {
        s_idx = 0x7fffffff;
        int is64 = 1;
        for (int i = 1; i < B * T; i += 2) {
            if (dates_sat_raw[i] != 0) { is64 = 0; break; }
        }
        s_is64 = is64;
    }
    __syncthreads();
    const int is64 = s_is64;

    const int target = is64 ? dates_sat_raw[2 * bt] : dates_sat_raw[bt];

    // first climate index whose date equals the sat date
    int local = 0x7fffffff;
    for (int j = tid; j < Tc; j += 64) {
        const int e = b * Tc + j;
        const int dc = is64 ? dates_clim_raw[2 * e] : dates_clim_raw[e];
        if (dc == target) local = min(local, j);
    }
    if (local != 0x7fffffff) atomicMin(&s_idx, local);
    __syncthreads();

    const int  idx = s_idx;
    const bool has = idx < Tc;

    if (tid < Dc) {
        s_clim[tid] = has ? input_clim[(b * Tc + idx) * Dc + tid] : PAD_VALUE;
    }
    __syncthreads();

    // hidden layer: h[tid] = relu(sum_d clim[d]*W1[d][tid] + b1[tid])
    float acc = b1[tid];
#pragma unroll
    for (int d = 0; d < Dc; ++d)
        acc += s_clim[d] * W1[d * HID + tid];
    s_h[tid] = fmaxf(acc, 0.0f);
    __syncthreads();

    // output layer: feat[tid] = sum_j h[j]*W2[j][tid] + b2[tid]
    float acc2 = b2[tid];
#pragma unroll
    for (int j = 0; j < HID; ++j)
        acc2 += s_h[j] * W2[j * Dm + tid];

    feat_out[bt * Dm + tid] = acc2;
}

// ---------------------------------------------------------------------------
// Kernel 2: assemble output [B,T,74,H,W] fp32.
// One block per (b,t,c) plane of 16384 floats; 256 threads x 16 iters of
// 16 B/lane non-temporal stores (pure streaming, zero reuse -> bypass L2
// allocate / RFO). Channels < C copy sat (NT loads); channels >= C splat
// one fp32 clim_feat value.
// ---------------------------------------------------------------------------
__global__ __launch_bounds__(256)
void assemble_kernel(const float* __restrict__ input_sat,  // [B*T*C*HW] fp32
                     const float* __restrict__ feat,       // [B*T*Dm] fp32
                     float* __restrict__ out) {            // [B*T*CO*HW] fp32
    const int plane = blockIdx.x;       // 0 .. B*T*CO-1
    const int c  = plane % CO;
    const int bt = plane / CO;

    vfloat4* __restrict__ dst4 = reinterpret_cast<vfloat4*>(out + (size_t)plane * HW);
    constexpr int NVEC = HW / 4;        // 4096 float4 per plane

    if (c < C) {
        const vfloat4* __restrict__ src4 = reinterpret_cast<const vfloat4*>(
            input_sat + (size_t)(bt * C + c) * HW);
        for (int i = threadIdx.x; i < NVEC; i += 256) {
            const vfloat4 v = __builtin_nontemporal_load(&src4[i]);
            __builtin_nontemporal_store(v, &dst4[i]);
        }
    } else {
        const float v = feat[bt * Dm + (c - C)];
        const vfloat4 splat = {v, v, v, v};
        for (int i = threadIdx.x; i < NVEC; i += 256)
            __builtin_nontemporal_store(splat, &dst4[i]);
    }
}

// ---------------------------------------------------------------------------
extern "C" void kernel_launch(void* const* d_in, const int* in_sizes, int n_in,
                              void* d_out, int out_size, void* d_ws, size_t ws_size,
                              hipStream_t stream) {
    const float* input_sat  = (const float*)d_in[0];
    const int*   dates_sat  = (const int*)d_in[1];
    const float* input_clim = (const float*)d_in[2];
    const int*   dates_clim = (const int*)d_in[3];
    const float* W1p        = (const float*)d_in[4];
    const float* b1p        = (const float*)d_in[5];
    const float* W2p        = (const float*)d_in[6];
    const float* b2p        = (const float*)d_in[7];

    float* feat = (float*)d_ws;    // B*T*Dm fp32 (24 KB scratch)
    float* out  = (float*)d_out;   // fp32 output (reference output dtype)

    clim_mlp_kernel<<<B * T, 64, 0, stream>>>(dates_sat, input_clim, dates_clim,
                                              W1p, b1p, W2p, b2p, feat);

    assemble_kernel<<<B * T * CO, 256, 0, stream>>>(input_sat, feat, out);
}